// Round 1
// baseline (487.120 us; speedup 1.0000x reference)
//
#include <hip/hip_runtime.h>
#include <math.h>

#define HW 16384
#define NPROJ 100
#define NB 8
#define EPSV 1e-6f

__global__ __launch_bounds__(64) void zero_out_kernel(float* out) {
    if (threadIdx.x == 0) out[0] = 0.0f;
}

// pc[j][p] = i * a_j + jc * b_j  with (a,b) the L2-normalized projection column j
__global__ __launch_bounds__(256) void pc_kernel(const float* __restrict__ proj,
                                                 float* __restrict__ pc) {
    int j = blockIdx.x;
    float a = proj[j];
    float b = proj[NPROJ + j];
    float inv = 1.0f / sqrtf(a * a + b * b);
    a *= inv; b *= inv;
    float* col = pc + (size_t)j * HW;
    for (int p = threadIdx.x; p < HW; p += 256) {
        float fi = (float)(p >> 7);
        float fj = (float)(p & 127);
        col[p] = fi * a + fj * b;
    }
}

// per-batch max/argmax of channel 0 (first-occurrence tie-break), EPS fix info
__global__ __launch_bounds__(256) void maxfix_kernel(const float* __restrict__ X,
                                                     float* __restrict__ fixAdd,
                                                     int* __restrict__ fixIdx) {
    int b = blockIdx.x;
    const float* x0 = X + (size_t)b * 3 * HW;
    float mv = -INFINITY;
    int mi = 0;
    for (int p = threadIdx.x; p < HW; p += 256) {
        float v = x0[p];
        if (v > mv) { mv = v; mi = p; }
    }
    __shared__ float smv[256];
    __shared__ int smi[256];
    smv[threadIdx.x] = mv;
    smi[threadIdx.x] = mi;
    __syncthreads();
    for (int s = 128; s > 0; s >>= 1) {
        if (threadIdx.x < s) {
            float ov = smv[threadIdx.x + s];
            int oi = smi[threadIdx.x + s];
            if (ov > smv[threadIdx.x] ||
                (ov == smv[threadIdx.x] && oi < smi[threadIdx.x])) {
                smv[threadIdx.x] = ov;
                smi[threadIdx.x] = oi;
            }
        }
        __syncthreads();
    }
    if (threadIdx.x == 0) {
        bool should = smv[0] < EPSV;
        fixAdd[b] = should ? (EPSV - smv[0]) : 0.0f;
        fixIdx[b] = smi[0];
    }
}

// Xm[b][p] = mean over 3 channels (with EPS fix on ch0), plus per-batch sums of Xm and Y[:,0]
__global__ __launch_bounds__(256) void prep_kernel(const float* __restrict__ X,
                                                   const float* __restrict__ Y,
                                                   const float* __restrict__ fixAdd,
                                                   const int* __restrict__ fixIdx,
                                                   float* __restrict__ Xm,
                                                   float* __restrict__ SX,
                                                   float* __restrict__ SY) {
    int b = blockIdx.x;
    const float* xb = X + (size_t)b * 3 * HW;
    const float* yb = Y + (size_t)b * 3 * HW;
    float fa = fixAdd[b];
    int fi = fixIdx[b];
    float sx = 0.0f, sy = 0.0f;
    for (int p = threadIdx.x; p < HW; p += 256) {
        float xm = (xb[p] + xb[HW + p] + xb[2 * HW + p]) * (1.0f / 3.0f);
        if (p == fi) xm += fa * (1.0f / 3.0f);
        Xm[b * HW + p] = xm;
        sx += xm;
        sy += yb[p];
    }
    __shared__ float ssx[256];
    __shared__ float ssy[256];
    ssx[threadIdx.x] = sx;
    ssy[threadIdx.x] = sy;
    __syncthreads();
    for (int s = 128; s > 0; s >>= 1) {
        if (threadIdx.x < s) {
            ssx[threadIdx.x] += ssx[threadIdx.x + s];
            ssy[threadIdx.x] += ssy[threadIdx.x + s];
        }
        __syncthreads();
    }
    if (threadIdx.x == 0) {
        SX[b] = ssx[0];
        SY[b] = ssy[0];
    }
}

// In-LDS bitonic argsort of one projection column (16384 keys + u16 indices = 96 KiB LDS).
// Writes keys back in place (pc becomes pc_sorted) and the permutation to sorter.
__global__ __launch_bounds__(1024) void sort_kernel(float* __restrict__ pc,
                                                    int* __restrict__ sorter) {
    __shared__ float skey[HW];
    __shared__ unsigned short sidx[HW];
    float* col = pc + (size_t)blockIdx.x * HW;
    int* srt = sorter + (size_t)blockIdx.x * HW;
    for (int i = threadIdx.x; i < HW; i += 1024) {
        skey[i] = col[i];
        sidx[i] = (unsigned short)i;
    }
    __syncthreads();
    for (int k = 2; k <= HW; k <<= 1) {
        for (int st = k >> 1; st > 0; st >>= 1) {
            for (int i = threadIdx.x; i < HW; i += 1024) {
                int ixj = i ^ st;
                if (ixj > i) {
                    float a = skey[i];
                    float c = skey[ixj];
                    bool asc = ((i & k) == 0);
                    if (asc ? (a > c) : (a < c)) {
                        skey[i] = c;
                        skey[ixj] = a;
                        unsigned short t = sidx[i];
                        sidx[i] = sidx[ixj];
                        sidx[ixj] = t;
                    }
                }
            }
            __syncthreads();
        }
    }
    for (int i = threadIdx.x; i < HW; i += 1024) {
        col[i] = skey[i];
        srt[i] = (int)sidx[i];
    }
}

// One block per (projection, batch): CDF-form W1 via hierarchical prefix scan.
__global__ __launch_bounds__(256) void w1_kernel(const float* __restrict__ Xm,
                                                 const float* __restrict__ Y,
                                                 const float* __restrict__ pcs,
                                                 const int* __restrict__ sorter,
                                                 const float* __restrict__ SX,
                                                 const float* __restrict__ SY,
                                                 float* __restrict__ out) {
    const int bj = blockIdx.x;
    const int j = bj >> 3;   // projection
    const int b = bj & 7;    // batch
    const int tid = threadIdx.x;
    const int lane = tid & 63;
    const int wid = tid >> 6;
    const float invSX = 1.0f / SX[b];
    const float invSY = 1.0f / SY[b];
    const float* __restrict__ xw = Xm + b * HW;
    const float* __restrict__ yw = Y + (size_t)b * 3 * HW;  // channel 0
    const int* __restrict__ srt = sorter + (size_t)j * HW;
    const float* __restrict__ pp = pcs + (size_t)j * HW;

    __shared__ float wtX[4];
    __shared__ float wtY[4];

    float runX = 0.0f, runY = 0.0f, acc = 0.0f;
    const int PER = 16;

    for (int s = 0; s < 4; ++s) {
        int base = s * 4096 + tid * PER;
        float xv[16], yv[16];
        float lx = 0.0f, ly = 0.0f;
#pragma unroll
        for (int m = 0; m < PER; ++m) {
            int idx = srt[base + m];
            lx += xw[idx]; xv[m] = lx;
            ly += yw[idx]; yv[m] = ly;
        }
        // wave-level inclusive scan of per-thread totals
        float ix = lx, iy = ly;
#pragma unroll
        for (int off = 1; off < 64; off <<= 1) {
            float nx = __shfl_up(ix, off);
            float ny = __shfl_up(iy, off);
            if (lane >= off) { ix += nx; iy += ny; }
        }
        if (lane == 63) { wtX[wid] = ix; wtY[wid] = iy; }
        __syncthreads();
        float preX = 0.0f, preY = 0.0f, tX = 0.0f, tY = 0.0f;
#pragma unroll
        for (int w = 0; w < 4; ++w) {
            float wx = wtX[w], wy = wtY[w];
            tX += wx; tY += wy;
            if (w < wid) { preX += wx; preY += wy; }
        }
        float offX = runX + preX + (ix - lx);  // exclusive prefix for this thread
        float offY = runY + preY + (iy - ly);
#pragma unroll
        for (int m = 0; m < PER; ++m) {
            int k = base + m;
            if (k < HW - 1) {
                float d = pp[k + 1] - pp[k];
                float cx = (offX + xv[m]) * invSX;
                float cy = (offY + yv[m]) * invSY;
                acc += fabsf(cx - cy) * d;
            }
        }
        runX += tX;
        runY += tY;
        __syncthreads();
    }

    // block reduce acc
#pragma unroll
    for (int off = 32; off > 0; off >>= 1) acc += __shfl_down(acc, off);
    if (lane == 0) wtX[wid] = acc;
    __syncthreads();
    if (tid == 0) {
        float r = wtX[0] + wtX[1] + wtX[2] + wtX[3];
        atomicAdd(out, r * (1.0f / NPROJ));
    }
}

extern "C" void kernel_launch(void* const* d_in, const int* in_sizes, int n_in,
                              void* d_out, int out_size, void* d_ws, size_t ws_size,
                              hipStream_t stream) {
    const float* X = (const float*)d_in[0];
    const float* Y = (const float*)d_in[1];
    const float* proj = (const float*)d_in[2];
    float* out = (float*)d_out;

    char* ws = (char*)d_ws;
    size_t off = 0;
    float* pc = (float*)(ws + off);      off += (size_t)NPROJ * HW * sizeof(float);
    int* sorter = (int*)(ws + off);      off += (size_t)NPROJ * HW * sizeof(int);
    float* Xm = (float*)(ws + off);      off += (size_t)NB * HW * sizeof(float);
    float* SX = (float*)(ws + off);      off += NB * sizeof(float);
    float* SY = (float*)(ws + off);      off += NB * sizeof(float);
    float* fixAdd = (float*)(ws + off);  off += NB * sizeof(float);
    int* fixIdx = (int*)(ws + off);      off += NB * sizeof(int);

    zero_out_kernel<<<1, 64, 0, stream>>>(out);
    pc_kernel<<<NPROJ, 256, 0, stream>>>(proj, pc);
    maxfix_kernel<<<NB, 256, 0, stream>>>(X, fixAdd, fixIdx);
    prep_kernel<<<NB, 256, 0, stream>>>(X, Y, fixAdd, fixIdx, Xm, SX, SY);
    sort_kernel<<<NPROJ, 1024, 0, stream>>>(pc, sorter);
    w1_kernel<<<NPROJ * NB, 256, 0, stream>>>(Xm, Y, pc, sorter, SX, SY, out);
}

// Round 2
// 148.758 us; speedup vs baseline: 3.2746x; 3.2746x over previous
//
#include <hip/hip_runtime.h>
#include <math.h>

#define HW 16384
#define NPROJ 100
#define NB 8
#define EPSV 1e-6f

__global__ __launch_bounds__(64) void zero_out_kernel(float* out) {
    if (threadIdx.x == 0) out[0] = 0.0f;
}

// per-batch max/argmax of channel 0 (first-occurrence tie-break), EPS fix info
__global__ __launch_bounds__(256) void maxfix_kernel(const float* __restrict__ X,
                                                     float* __restrict__ fixAdd,
                                                     int* __restrict__ fixIdx) {
    int b = blockIdx.x;
    const float* x0 = X + (size_t)b * 3 * HW;
    float mv = -INFINITY;
    int mi = 0;
    for (int p = threadIdx.x; p < HW; p += 256) {
        float v = x0[p];
        if (v > mv) { mv = v; mi = p; }
    }
    __shared__ float smv[256];
    __shared__ int smi[256];
    smv[threadIdx.x] = mv;
    smi[threadIdx.x] = mi;
    __syncthreads();
    for (int s = 128; s > 0; s >>= 1) {
        if (threadIdx.x < s) {
            float ov = smv[threadIdx.x + s];
            int oi = smi[threadIdx.x + s];
            if (ov > smv[threadIdx.x] ||
                (ov == smv[threadIdx.x] && oi < smi[threadIdx.x])) {
                smv[threadIdx.x] = ov;
                smi[threadIdx.x] = oi;
            }
        }
        __syncthreads();
    }
    if (threadIdx.x == 0) {
        bool should = smv[0] < EPSV;
        fixAdd[b] = should ? (EPSV - smv[0]) : 0.0f;
        fixIdx[b] = smi[0];
    }
}

// Xm[b][p] = mean over 3 channels (with EPS fix on ch0), plus per-batch sums of Xm and Y[:,0]
__global__ __launch_bounds__(256) void prep_kernel(const float* __restrict__ X,
                                                   const float* __restrict__ Y,
                                                   const float* __restrict__ fixAdd,
                                                   const int* __restrict__ fixIdx,
                                                   float* __restrict__ Xm,
                                                   float* __restrict__ SX,
                                                   float* __restrict__ SY) {
    int b = blockIdx.x;
    const float* xb = X + (size_t)b * 3 * HW;
    const float* yb = Y + (size_t)b * 3 * HW;
    float fa = fixAdd[b];
    int fi = fixIdx[b];
    float sx = 0.0f, sy = 0.0f;
    for (int p = threadIdx.x; p < HW; p += 256) {
        float xm = (xb[p] + xb[HW + p] + xb[2 * HW + p]) * (1.0f / 3.0f);
        if (p == fi) xm += fa * (1.0f / 3.0f);
        Xm[b * HW + p] = xm;
        sx += xm;
        sy += yb[p];
    }
    __shared__ float ssx[256];
    __shared__ float ssy[256];
    ssx[threadIdx.x] = sx;
    ssy[threadIdx.x] = sy;
    __syncthreads();
    for (int s = 128; s > 0; s >>= 1) {
        if (threadIdx.x < s) {
            ssx[threadIdx.x] += ssx[threadIdx.x + s];
            ssy[threadIdx.x] += ssy[threadIdx.x + s];
        }
        __syncthreads();
    }
    if (threadIdx.x == 0) {
        SX[b] = ssx[0];
        SY[b] = ssy[0];
    }
}

// Analytic argsort of pc[i][j] = i*an + j*bn using the arithmetic-progression
// structure: rank = sliding-window sum of c_d = ceil(d*|a|/|b|) tables, plus a
// tie-count for exact integer d*r. One block per projection; writes pcs_sorted
// and sorter directly (no comparison sort).
__global__ __launch_bounds__(256) void ranksort_kernel(const float* __restrict__ proj,
                                                       float* __restrict__ pcs,
                                                       int* __restrict__ sorter) {
    const int jp = blockIdx.x;
    float a = proj[jp];
    float b = proj[NPROJ + jp];
    float inv = 1.0f / sqrtf(a * a + b * b);
    const float an = a * inv, bn = b * inv;
    const float ap = fabsf(an), bp = fabsf(bn);
    const bool flipi = (an < 0.0f), flipj = (bn < 0.0f);

    float* __restrict__ pcol = pcs + (size_t)jp * HW;
    int* __restrict__ scol = sorter + (size_t)jp * HW;

    if (bp == 0.0f) {
        // degenerate: value depends only on i2; pos = i2*128 + j2
        for (int t = threadIdx.x; t < HW; t += 256) {
            int i2 = t >> 7, j2 = t & 127;
            int ii = flipi ? 127 - i2 : i2;
            int jj = flipj ? 127 - j2 : j2;
            float val = (float)ii * an + (float)jj * bn;
            scol[t] = ii * 128 + jj;
            pcol[t] = val;
        }
        return;
    }

    __shared__ int c_t[255];           // clamp(ceil(d*r), -128, 129), d = dd-127
    __shared__ unsigned char e_t[255]; // 1 if d*r exactly integral
    const double r = (double)ap / (double)bp;
    for (int dd = threadIdx.x; dd < 255; dd += 256) {
        int d = dd - 127;
        double v = (double)d * r;
        double cv = ceil(v);
        e_t[dd] = (cv == v) ? 1 : 0;
        double cc = fmin(fmax(cv, -128.0), 129.0);
        c_t[dd] = (int)cc;
    }
    __syncthreads();

    if (threadIdx.x < 128) {
        const int j2 = threadIdx.x;
        const int jj = flipj ? 127 - j2 : j2;
        const float vj = (float)jj * bn;

        // window sum for i2 = 0: d in [-127, 0]  (dd = 0..127)
        int wsum = 0;
#pragma unroll 8
        for (int dd = 0; dd <= 127; ++dd)
            wsum += min(max(c_t[dd] + j2, 0), 128);
        int tsum = 0;

        for (int i2 = 0; i2 < 128; ++i2) {
            if (i2 > 0) {
                int dd_new = i2 + 127;   // d = i2 enters window
                int dd_old = i2 - 1;     // d = i2-128 leaves window
                int cn = c_t[dd_new];
                wsum += min(max(cn + j2, 0), 128);
                wsum -= min(max(c_t[dd_old] + j2, 0), 128);
                if (e_t[dd_new]) {       // tie with row i2' = 0..i2-1 at j' = j2 + d*r
                    int tj = j2 + cn;
                    if (tj >= 0 && tj < 128) tsum++;
                }
            }
            int pos = wsum + tsum;
            int ii = flipi ? 127 - i2 : i2;
            float val = (float)ii * an + vj;
            scol[pos] = ii * 128 + jj;
            pcol[pos] = val;
        }
    }
}

// One block per (projection, batch): CDF-form W1 via hierarchical prefix scan.
__global__ __launch_bounds__(256) void w1_kernel(const float* __restrict__ Xm,
                                                 const float* __restrict__ Y,
                                                 const float* __restrict__ pcs,
                                                 const int* __restrict__ sorter,
                                                 const float* __restrict__ SX,
                                                 const float* __restrict__ SY,
                                                 float* __restrict__ out) {
    const int bj = blockIdx.x;
    const int j = bj >> 3;   // projection
    const int b = bj & 7;    // batch
    const int tid = threadIdx.x;
    const int lane = tid & 63;
    const int wid = tid >> 6;
    const float invSX = 1.0f / SX[b];
    const float invSY = 1.0f / SY[b];
    const float* __restrict__ xw = Xm + b * HW;
    const float* __restrict__ yw = Y + (size_t)b * 3 * HW;  // channel 0
    const int* __restrict__ srt = sorter + (size_t)j * HW;
    const float* __restrict__ pp = pcs + (size_t)j * HW;

    __shared__ float wtX[4];
    __shared__ float wtY[4];

    float runX = 0.0f, runY = 0.0f, acc = 0.0f;
    const int PER = 16;

    for (int s = 0; s < 4; ++s) {
        int base = s * 4096 + tid * PER;
        float xv[16], yv[16];
        float lx = 0.0f, ly = 0.0f;
#pragma unroll
        for (int m = 0; m < PER; ++m) {
            int idx = srt[base + m];
            lx += xw[idx]; xv[m] = lx;
            ly += yw[idx]; yv[m] = ly;
        }
        // wave-level inclusive scan of per-thread totals
        float ix = lx, iy = ly;
#pragma unroll
        for (int off = 1; off < 64; off <<= 1) {
            float nx = __shfl_up(ix, off);
            float ny = __shfl_up(iy, off);
            if (lane >= off) { ix += nx; iy += ny; }
        }
        if (lane == 63) { wtX[wid] = ix; wtY[wid] = iy; }
        __syncthreads();
        float preX = 0.0f, preY = 0.0f, tX = 0.0f, tY = 0.0f;
#pragma unroll
        for (int w = 0; w < 4; ++w) {
            float wx = wtX[w], wy = wtY[w];
            tX += wx; tY += wy;
            if (w < wid) { preX += wx; preY += wy; }
        }
        float offX = runX + preX + (ix - lx);  // exclusive prefix for this thread
        float offY = runY + preY + (iy - ly);
#pragma unroll
        for (int m = 0; m < PER; ++m) {
            int k = base + m;
            if (k < HW - 1) {
                float d = pp[k + 1] - pp[k];
                float cx = (offX + xv[m]) * invSX;
                float cy = (offY + yv[m]) * invSY;
                acc += fabsf(cx - cy) * d;
            }
        }
        runX += tX;
        runY += tY;
        __syncthreads();
    }

    // block reduce acc
#pragma unroll
    for (int off = 32; off > 0; off >>= 1) acc += __shfl_down(acc, off);
    if (lane == 0) wtX[wid] = acc;
    __syncthreads();
    if (tid == 0) {
        float r = wtX[0] + wtX[1] + wtX[2] + wtX[3];
        atomicAdd(out, r * (1.0f / NPROJ));
    }
}

extern "C" void kernel_launch(void* const* d_in, const int* in_sizes, int n_in,
                              void* d_out, int out_size, void* d_ws, size_t ws_size,
                              hipStream_t stream) {
    const float* X = (const float*)d_in[0];
    const float* Y = (const float*)d_in[1];
    const float* proj = (const float*)d_in[2];
    float* out = (float*)d_out;

    char* ws = (char*)d_ws;
    size_t off = 0;
    float* pcs = (float*)(ws + off);     off += (size_t)NPROJ * HW * sizeof(float);
    int* sorter = (int*)(ws + off);      off += (size_t)NPROJ * HW * sizeof(int);
    float* Xm = (float*)(ws + off);      off += (size_t)NB * HW * sizeof(float);
    float* SX = (float*)(ws + off);      off += NB * sizeof(float);
    float* SY = (float*)(ws + off);      off += NB * sizeof(float);
    float* fixAdd = (float*)(ws + off);  off += NB * sizeof(float);
    int* fixIdx = (int*)(ws + off);      off += NB * sizeof(int);

    zero_out_kernel<<<1, 64, 0, stream>>>(out);
    maxfix_kernel<<<NB, 256, 0, stream>>>(X, fixAdd, fixIdx);
    prep_kernel<<<NB, 256, 0, stream>>>(X, Y, fixAdd, fixIdx, Xm, SX, SY);
    ranksort_kernel<<<NPROJ, 256, 0, stream>>>(proj, pcs, sorter);
    w1_kernel<<<NPROJ * NB, 256, 0, stream>>>(Xm, Y, pcs, sorter, SX, SY, out);
}

// Round 3
// 87.511 us; speedup vs baseline: 5.5664x; 1.6999x over previous
//
#include <hip/hip_runtime.h>
#include <math.h>

#define HW 16384
#define NPROJ 100
#define NB 8
#define NSEG 16
#define SEGLEN 1024
#define EPSV 1e-6f

__device__ inline float4 add4(float4 a, float4 b) {
    return make_float4(a.x + b.x, a.y + b.y, a.z + b.z, a.w + b.w);
}
__device__ inline float4 sub4(float4 a, float4 b) {
    return make_float4(a.x - b.x, a.y - b.y, a.z - b.z, a.w - b.w);
}
__device__ inline float4 shfl_up4(float4 v, int off) {
    return make_float4(__shfl_up(v.x, off), __shfl_up(v.y, off),
                       __shfl_up(v.z, off), __shfl_up(v.w, off));
}
__device__ inline float4 shfl_down4(float4 v, int off) {
    return make_float4(__shfl_down(v.x, off), __shfl_down(v.y, off),
                       __shfl_down(v.z, off), __shfl_down(v.w, off));
}

// Fused: zero output, per-batch ch0 max/argmax + EPS fix, Xm mean, SX/SY sums.
__global__ __launch_bounds__(256) void prep_kernel(const float* __restrict__ X,
                                                   const float* __restrict__ Y,
                                                   float* __restrict__ Xm,
                                                   float* __restrict__ SX,
                                                   float* __restrict__ SY,
                                                   float* __restrict__ out) {
    const int b = blockIdx.x;
    const int tid = threadIdx.x;
    if (b == 0 && tid == 0) out[0] = 0.0f;  // safe: atomicAdds happen in a later kernel
    const float* xb = X + (size_t)b * 3 * HW;
    const float* yb = Y + (size_t)b * 3 * HW;

    // phase 1: max/argmax of channel 0 (first-occurrence tie-break)
    float mv = -INFINITY;
    int mi = 0;
    for (int p = tid; p < HW; p += 256) {
        float v = xb[p];
        if (v > mv) { mv = v; mi = p; }
    }
    __shared__ float smv[256];
    __shared__ int smi[256];
    smv[tid] = mv;
    smi[tid] = mi;
    __syncthreads();
    for (int s = 128; s > 0; s >>= 1) {
        if (tid < s) {
            float ov = smv[tid + s];
            int oi = smi[tid + s];
            if (ov > smv[tid] || (ov == smv[tid] && oi < smi[tid])) {
                smv[tid] = ov;
                smi[tid] = oi;
            }
        }
        __syncthreads();
    }
    const float fa = (smv[0] < EPSV) ? (EPSV - smv[0]) : 0.0f;
    const int fi = smi[0];
    __syncthreads();

    // phase 2: Xm + sums
    __shared__ float ssx[256];
    __shared__ float ssy[256];
    float sx = 0.0f, sy = 0.0f;
    for (int p = tid; p < HW; p += 256) {
        float xm = (xb[p] + xb[HW + p] + xb[2 * HW + p]) * (1.0f / 3.0f);
        if (p == fi) xm += fa * (1.0f / 3.0f);
        Xm[b * HW + p] = xm;
        sx += xm;
        sy += yb[p];
    }
    ssx[tid] = sx;
    ssy[tid] = sy;
    __syncthreads();
    for (int s = 128; s > 0; s >>= 1) {
        if (tid < s) {
            ssx[tid] += ssx[tid + s];
            ssy[tid] += ssy[tid + s];
        }
        __syncthreads();
    }
    if (tid == 0) {
        SX[b] = ssx[0];
        SY[b] = ssy[0];
    }
}

// Z[p][b] = Xm[b][p]/SX[b] - Y0[b][p]/SY[b], pixel-major float8 (32B per pixel).
__global__ __launch_bounds__(256) void zprep_kernel(const float* __restrict__ Xm,
                                                    const float* __restrict__ Y,
                                                    const float* __restrict__ SX,
                                                    const float* __restrict__ SY,
                                                    float* __restrict__ Z) {
    const int p = blockIdx.x * 256 + threadIdx.x;
    float z[8];
#pragma unroll
    for (int b = 0; b < 8; ++b) {
        float invx = 1.0f / SX[b];
        float invy = 1.0f / SY[b];
        z[b] = Xm[b * HW + p] * invx - Y[(size_t)b * 3 * HW + p] * invy;
    }
    float4* zp = (float4*)(Z + (size_t)p * 8);
    zp[0] = make_float4(z[0], z[1], z[2], z[3]);
    zp[1] = make_float4(z[4], z[5], z[6], z[7]);
}

// Analytic argsort of pc[i][j] = i*an + j*bn (arithmetic-progression structure):
// rank = sliding-window sum over c_d = ceil(d*r) table + tie counts. Scatter to
// LDS, then coalesced global write-out.
__global__ __launch_bounds__(256) void ranksort_kernel(const float* __restrict__ proj,
                                                       float* __restrict__ pcs,
                                                       int* __restrict__ sorter) {
    const int jp = blockIdx.x;
    float a = proj[jp];
    float b = proj[NPROJ + jp];
    float inv = 1.0f / sqrtf(a * a + b * b);
    const float an = a * inv, bn = b * inv;
    const float ap = fabsf(an), bp = fabsf(bn);
    const bool flipi = (an < 0.0f), flipj = (bn < 0.0f);

    float* __restrict__ pcol = pcs + (size_t)jp * HW;
    int* __restrict__ scol = sorter + (size_t)jp * HW;

    if (bp == 0.0f) {
        for (int t = threadIdx.x; t < HW; t += 256) {
            int i2 = t >> 7, j2 = t & 127;
            int ii = flipi ? 127 - i2 : i2;
            int jj = flipj ? 127 - j2 : j2;
            scol[t] = ii * 128 + jj;
            pcol[t] = (float)ii * an + (float)jj * bn;
        }
        return;
    }

    __shared__ int c_t[255];
    __shared__ unsigned char e_t[255];
    __shared__ float spc[HW];            // 64 KiB
    __shared__ unsigned short sid[HW];   // 32 KiB
    const double r = (double)ap / (double)bp;
    for (int dd = threadIdx.x; dd < 255; dd += 256) {
        int d = dd - 127;
        double v = (double)d * r;
        double cv = ceil(v);
        e_t[dd] = (cv == v) ? 1 : 0;
        c_t[dd] = (int)fmin(fmax(cv, -128.0), 129.0);
    }
    __syncthreads();

    if (threadIdx.x < 128) {
        const int j2 = threadIdx.x;
        const int jj = flipj ? 127 - j2 : j2;
        const float vj = (float)jj * bn;

        int wsum = 0;
#pragma unroll 8
        for (int dd = 0; dd <= 127; ++dd)
            wsum += min(max(c_t[dd] + j2, 0), 128);
        int tsum = 0;

        for (int i2 = 0; i2 < 128; ++i2) {
            if (i2 > 0) {
                int dd_new = i2 + 127;
                int dd_old = i2 - 1;
                int cn = c_t[dd_new];
                wsum += min(max(cn + j2, 0), 128);
                wsum -= min(max(c_t[dd_old] + j2, 0), 128);
                if (e_t[dd_new]) {
                    int tj = j2 + cn;
                    if (tj >= 0 && tj < 128) tsum++;
                }
            }
            int pos = wsum + tsum;
            int ii = flipi ? 127 - i2 : i2;
            spc[pos] = (float)ii * an + vj;
            sid[pos] = (unsigned short)(ii * 128 + jj);
        }
    }
    __syncthreads();
    for (int t = threadIdx.x; t < HW; t += 256) {
        pcol[t] = spc[t];
        scol[t] = (int)sid[t];
    }
}

// Per-(proj,segment) 8-channel segment totals of gathered Z.
__global__ __launch_bounds__(256) void segsum_kernel(const int* __restrict__ sorter,
                                                     const float* __restrict__ Z,
                                                     float* __restrict__ T) {
    const int blk = blockIdx.x;
    const int j = blk >> 4, s = blk & 15;
    const int tid = threadIdx.x, lane = tid & 63, wid = tid >> 6;
    const int* srt = sorter + (size_t)j * HW + s * SEGLEN;
    int4 id4 = *(const int4*)(srt + tid * 4);
    int ids[4] = {id4.x, id4.y, id4.z, id4.w};
    float4 sa = make_float4(0, 0, 0, 0), sb = sa;
#pragma unroll
    for (int m = 0; m < 4; ++m) {
        const float4* zp = (const float4*)(Z + (size_t)ids[m] * 8);
        sa = add4(sa, zp[0]);
        sb = add4(sb, zp[1]);
    }
#pragma unroll
    for (int off = 32; off > 0; off >>= 1) {
        sa = add4(sa, shfl_down4(sa, off));
        sb = add4(sb, shfl_down4(sb, off));
    }
    __shared__ float4 la[4], lb[4];
    if (lane == 0) { la[wid] = sa; lb[wid] = sb; }
    __syncthreads();
    if (tid == 0) {
        float4 ta = la[0], tb = lb[0];
        for (int w = 1; w < 4; ++w) { ta = add4(ta, la[w]); tb = add4(tb, lb[w]); }
        float* tp = T + (size_t)blk * 8;
        tp[0] = ta.x; tp[1] = ta.y; tp[2] = ta.z; tp[3] = ta.w;
        tp[4] = tb.x; tp[5] = tb.y; tp[6] = tb.z; tp[7] = tb.w;
    }
}

// Exclusive scan of segment totals across the 16 segments of each projection.
__global__ __launch_bounds__(64) void segscan_kernel(const float* __restrict__ T,
                                                     float* __restrict__ Cc) {
    const int j = blockIdx.x, b = threadIdx.x;
    if (b < 8) {
        float run = 0.0f;
        for (int s = 0; s < NSEG; ++s) {
            size_t o = ((size_t)(j * NSEG + s)) * 8 + b;
            Cc[o] = run;
            run += T[o];
        }
    }
}

// Per-(proj,segment) 8-channel in-block scan + CDF-difference integral.
__global__ __launch_bounds__(256) void w1seg_kernel(const int* __restrict__ sorter,
                                                    const float* __restrict__ Z,
                                                    const float* __restrict__ pcs,
                                                    const float* __restrict__ Cc,
                                                    float* __restrict__ out) {
    const int blk = blockIdx.x;
    const int j = blk >> 4, s = blk & 15;
    const int tid = threadIdx.x, lane = tid & 63, wid = tid >> 6;
    const int base_g = s * SEGLEN + tid * 4;
    const int* srt = sorter + (size_t)j * HW;
    const float* pp = pcs + (size_t)j * HW;

    int4 id4 = *(const int4*)(srt + base_g);
    int ids[4] = {id4.x, id4.y, id4.z, id4.w};
    float4 za[4], zb[4];
#pragma unroll
    for (int m = 0; m < 4; ++m) {
        const float4* zp = (const float4*)(Z + (size_t)ids[m] * 8);
        za[m] = zp[0];
        zb[m] = zp[1];
    }
#pragma unroll
    for (int m = 1; m < 4; ++m) {
        za[m] = add4(za[m], za[m - 1]);
        zb[m] = add4(zb[m], zb[m - 1]);
    }
    const float4 tota = za[3], totb = zb[3];
    float4 ia = tota, ib = totb;
#pragma unroll
    for (int off = 1; off < 64; off <<= 1) {
        float4 ua = shfl_up4(ia, off);
        float4 ub = shfl_up4(ib, off);
        if (lane >= off) { ia = add4(ia, ua); ib = add4(ib, ub); }
    }
    __shared__ float4 lwa[4], lwb[4];
    __shared__ float lred[4];
    if (lane == 63) { lwa[wid] = ia; lwb[wid] = ib; }
    __syncthreads();
    const float* cp = Cc + (size_t)blk * 8;
    float4 ca = make_float4(cp[0], cp[1], cp[2], cp[3]);
    float4 cb = make_float4(cp[4], cp[5], cp[6], cp[7]);
#pragma unroll
    for (int w = 0; w < 4; ++w)
        if (w < wid) { ca = add4(ca, lwa[w]); cb = add4(cb, lwb[w]); }
    const float4 offa = add4(ca, sub4(ia, tota));
    const float4 offb = add4(cb, sub4(ib, totb));

    float4 p4 = *(const float4*)(pp + base_g);
    float p5 = (base_g + 4 < HW) ? pp[base_g + 4] : p4.w;
    float dd[4] = {p4.y - p4.x, p4.z - p4.y, p4.w - p4.z, p5 - p4.w};

    float accl = 0.0f;
#pragma unroll
    for (int m = 0; m < 4; ++m) {
        float4 cxa = add4(offa, za[m]);
        float4 cxb = add4(offb, zb[m]);
        float s8 = fabsf(cxa.x) + fabsf(cxa.y) + fabsf(cxa.z) + fabsf(cxa.w)
                 + fabsf(cxb.x) + fabsf(cxb.y) + fabsf(cxb.z) + fabsf(cxb.w);
        if (base_g + m < HW - 1) accl += s8 * dd[m];
    }
#pragma unroll
    for (int off = 32; off > 0; off >>= 1) accl += __shfl_down(accl, off);
    if (lane == 0) lred[wid] = accl;
    __syncthreads();
    if (tid == 0)
        atomicAdd(out, (lred[0] + lred[1] + lred[2] + lred[3]) * (1.0f / NPROJ));
}

extern "C" void kernel_launch(void* const* d_in, const int* in_sizes, int n_in,
                              void* d_out, int out_size, void* d_ws, size_t ws_size,
                              hipStream_t stream) {
    const float* X = (const float*)d_in[0];
    const float* Y = (const float*)d_in[1];
    const float* proj = (const float*)d_in[2];
    float* out = (float*)d_out;

    char* ws = (char*)d_ws;
    size_t off = 0;
    float* pcs = (float*)(ws + off);    off += (size_t)NPROJ * HW * sizeof(float);
    int* sorter = (int*)(ws + off);     off += (size_t)NPROJ * HW * sizeof(int);
    float* Xm = (float*)(ws + off);     off += (size_t)NB * HW * sizeof(float);
    float* Z = (float*)(ws + off);      off += (size_t)NB * HW * sizeof(float);
    float* T = (float*)(ws + off);      off += (size_t)NPROJ * NSEG * 8 * sizeof(float);
    float* Cc = (float*)(ws + off);     off += (size_t)NPROJ * NSEG * 8 * sizeof(float);
    float* SX = (float*)(ws + off);     off += NB * sizeof(float);
    float* SY = (float*)(ws + off);     off += NB * sizeof(float);

    prep_kernel<<<NB, 256, 0, stream>>>(X, Y, Xm, SX, SY, out);
    zprep_kernel<<<HW / 256, 256, 0, stream>>>(Xm, Y, SX, SY, Z);
    ranksort_kernel<<<NPROJ, 256, 0, stream>>>(proj, pcs, sorter);
    segsum_kernel<<<NPROJ * NSEG, 256, 0, stream>>>(sorter, Z, T);
    segscan_kernel<<<NPROJ, 64, 0, stream>>>(T, Cc);
    w1seg_kernel<<<NPROJ * NSEG, 256, 0, stream>>>(sorter, Z, pcs, Cc, out);
}

// Round 4
// 74.720 us; speedup vs baseline: 6.5193x; 1.1712x over previous
//
#include <hip/hip_runtime.h>
#include <math.h>

#define HW 16384
#define NPROJ 100
#define NB 8
#define NSEG 16
#define SEGLEN 1024
#define NCH 32
#define CHLEN 512
#define EPSV 1e-6f

__device__ inline float4 add4(float4 a, float4 b) {
    return make_float4(a.x + b.x, a.y + b.y, a.z + b.z, a.w + b.w);
}
__device__ inline float4 sub4(float4 a, float4 b) {
    return make_float4(a.x - b.x, a.y - b.y, a.z - b.z, a.w - b.w);
}
__device__ inline float4 shfl_up4(float4 v, int off) {
    return make_float4(__shfl_up(v.x, off), __shfl_up(v.y, off),
                       __shfl_up(v.z, off), __shfl_up(v.w, off));
}
__device__ inline float4 shfl_down4(float4 v, int off) {
    return make_float4(__shfl_down(v.x, off), __shfl_down(v.y, off),
                       __shfl_down(v.z, off), __shfl_down(v.w, off));
}

// Stage 1: per-(batch, chunk) partials: Xs = x0+x1+x2 (stored), sum(Xs), sum(y0),
// chunk max/argmax of x0 (first-occurrence).
__global__ __launch_bounds__(256) void partial_kernel(const float* __restrict__ X,
                                                      const float* __restrict__ Y,
                                                      float* __restrict__ Xs,
                                                      float* __restrict__ Pmax,
                                                      int* __restrict__ Pidx,
                                                      float* __restrict__ Psx,
                                                      float* __restrict__ Psy) {
    const int blk = blockIdx.x;
    const int b = blk >> 5, c = blk & 31;
    const int tid = threadIdx.x, lane = tid & 63, wid = tid >> 6;
    const float* xb = X + (size_t)b * 3 * HW;
    const float* yb = Y + (size_t)b * 3 * HW;
    const int base = c * CHLEN;

    float mv = -INFINITY;
    int mi = 0;
    float sx = 0.0f, sy = 0.0f;
#pragma unroll
    for (int k = 0; k < 2; ++k) {
        int p = base + k * 256 + tid;
        float x0 = xb[p], x1 = xb[HW + p], x2 = xb[2 * HW + p], y0 = yb[p];
        float s = x0 + x1 + x2;
        Xs[(size_t)b * HW + p] = s;
        sx += s;
        sy += y0;
        if (x0 > mv) { mv = x0; mi = p; }   // strict > keeps earliest p
    }
    // wave reduce
#pragma unroll
    for (int off = 32; off > 0; off >>= 1) {
        float ov = __shfl_down(mv, off);
        int oi = __shfl_down(mi, off);
        sx += __shfl_down(sx, off);
        sy += __shfl_down(sy, off);
        if (ov > mv || (ov == mv && oi < mi)) { mv = ov; mi = oi; }
    }
    __shared__ float lmv[4], lsx[4], lsy[4];
    __shared__ int lmi[4];
    if (lane == 0) { lmv[wid] = mv; lmi[wid] = mi; lsx[wid] = sx; lsy[wid] = sy; }
    __syncthreads();
    if (tid == 0) {
        for (int w = 1; w < 4; ++w) {
            if (lmv[w] > lmv[0] || (lmv[w] == lmv[0] && lmi[w] < lmi[0])) {
                lmv[0] = lmv[w];
                lmi[0] = lmi[w];
            }
            lsx[0] += lsx[w];
            lsy[0] += lsy[w];
        }
        Pmax[blk] = lmv[0];
        Pidx[blk] = lmi[0];
        Psx[blk] = lsx[0];
        Psy[blk] = lsy[0];
    }
}

// Stage 2: reduce 32 chunk-partials per batch -> fa, fi, invX, invY; zero out.
__global__ __launch_bounds__(256) void combine_kernel(const float* __restrict__ Pmax,
                                                      const int* __restrict__ Pidx,
                                                      const float* __restrict__ Psx,
                                                      const float* __restrict__ Psy,
                                                      float* __restrict__ fixAdd,
                                                      int* __restrict__ fixIdx,
                                                      float* __restrict__ invX,
                                                      float* __restrict__ invY,
                                                      float* __restrict__ out) {
    const int tid = threadIdx.x;
    const int b = tid >> 5, c = tid & 31;
    float mv = Pmax[b * 32 + c];
    int mi = Pidx[b * 32 + c];
    float sx = Psx[b * 32 + c];
    float sy = Psy[b * 32 + c];
#pragma unroll
    for (int off = 16; off > 0; off >>= 1) {
        float ov = __shfl_down(mv, off, 32);
        int oi = __shfl_down(mi, off, 32);
        float osx = __shfl_down(sx, off, 32);
        float osy = __shfl_down(sy, off, 32);
        if (ov > mv || (ov == mv && oi < mi)) { mv = ov; mi = oi; }
        sx += osx;
        sy += osy;
    }
    if (c == 0) {
        float fa = (mv < EPSV) ? (EPSV - mv) : 0.0f;
        fixAdd[b] = fa;
        fixIdx[b] = mi;
        invX[b] = 1.0f / (sx + fa);
        invY[b] = 1.0f / sy;
    }
    if (tid == 0) out[0] = 0.0f;
}

// Stage 3: Z[p][b] = (Xs+fix)*invX - Y0*invY, pixel-major float8 (32B/pixel).
__global__ __launch_bounds__(64) void zprep_kernel(const float* __restrict__ Xs,
                                                   const float* __restrict__ Y,
                                                   const float* __restrict__ fixAdd,
                                                   const int* __restrict__ fixIdx,
                                                   const float* __restrict__ invX,
                                                   const float* __restrict__ invY,
                                                   float* __restrict__ Z) {
    const int p = blockIdx.x * 64 + threadIdx.x;
    float z[8];
#pragma unroll
    for (int b = 0; b < 8; ++b) {
        float s = Xs[(size_t)b * HW + p];
        if (p == fixIdx[b]) s += fixAdd[b];
        z[b] = s * invX[b] - Y[(size_t)b * 3 * HW + p] * invY[b];
    }
    float4* zp = (float4*)(Z + (size_t)p * 8);
    zp[0] = make_float4(z[0], z[1], z[2], z[3]);
    zp[1] = make_float4(z[4], z[5], z[6], z[7]);
}

// Analytic argsort of pc[i][j] = i*an + j*bn (arithmetic-progression structure):
// rank = sliding-window sum over c_d = ceil(d*r) table + tie counts. Scatter to
// LDS, then coalesced global write-out.
__global__ __launch_bounds__(256) void ranksort_kernel(const float* __restrict__ proj,
                                                       float* __restrict__ pcs,
                                                       int* __restrict__ sorter) {
    const int jp = blockIdx.x;
    float a = proj[jp];
    float b = proj[NPROJ + jp];
    float inv = 1.0f / sqrtf(a * a + b * b);
    const float an = a * inv, bn = b * inv;
    const float ap = fabsf(an), bp = fabsf(bn);
    const bool flipi = (an < 0.0f), flipj = (bn < 0.0f);

    float* __restrict__ pcol = pcs + (size_t)jp * HW;
    int* __restrict__ scol = sorter + (size_t)jp * HW;

    if (bp == 0.0f) {
        for (int t = threadIdx.x; t < HW; t += 256) {
            int i2 = t >> 7, j2 = t & 127;
            int ii = flipi ? 127 - i2 : i2;
            int jj = flipj ? 127 - j2 : j2;
            scol[t] = ii * 128 + jj;
            pcol[t] = (float)ii * an + (float)jj * bn;
        }
        return;
    }

    __shared__ int c_t[255];
    __shared__ unsigned char e_t[255];
    __shared__ float spc[HW];            // 64 KiB
    __shared__ unsigned short sid[HW];   // 32 KiB
    const double r = (double)ap / (double)bp;
    for (int dd = threadIdx.x; dd < 255; dd += 256) {
        int d = dd - 127;
        double v = (double)d * r;
        double cv = ceil(v);
        e_t[dd] = (cv == v) ? 1 : 0;
        c_t[dd] = (int)fmin(fmax(cv, -128.0), 129.0);
    }
    __syncthreads();

    if (threadIdx.x < 128) {
        const int j2 = threadIdx.x;
        const int jj = flipj ? 127 - j2 : j2;
        const float vj = (float)jj * bn;

        int wsum = 0;
#pragma unroll 8
        for (int dd = 0; dd <= 127; ++dd)
            wsum += min(max(c_t[dd] + j2, 0), 128);
        int tsum = 0;

        for (int i2 = 0; i2 < 128; ++i2) {
            if (i2 > 0) {
                int dd_new = i2 + 127;
                int dd_old = i2 - 1;
                int cn = c_t[dd_new];
                wsum += min(max(cn + j2, 0), 128);
                wsum -= min(max(c_t[dd_old] + j2, 0), 128);
                if (e_t[dd_new]) {
                    int tj = j2 + cn;
                    if (tj >= 0 && tj < 128) tsum++;
                }
            }
            int pos = wsum + tsum;
            int ii = flipi ? 127 - i2 : i2;
            spc[pos] = (float)ii * an + vj;
            sid[pos] = (unsigned short)(ii * 128 + jj);
        }
    }
    __syncthreads();
    for (int t = threadIdx.x; t < HW; t += 256) {
        pcol[t] = spc[t];
        scol[t] = (int)sid[t];
    }
}

// Per-(proj,segment) 8-channel segment totals of gathered Z.
__global__ __launch_bounds__(256) void segsum_kernel(const int* __restrict__ sorter,
                                                     const float* __restrict__ Z,
                                                     float* __restrict__ T) {
    const int blk = blockIdx.x;
    const int j = blk >> 4, s = blk & 15;
    const int tid = threadIdx.x, lane = tid & 63, wid = tid >> 6;
    const int* srt = sorter + (size_t)j * HW + s * SEGLEN;
    int4 id4 = *(const int4*)(srt + tid * 4);
    int ids[4] = {id4.x, id4.y, id4.z, id4.w};
    float4 sa = make_float4(0, 0, 0, 0), sb = sa;
#pragma unroll
    for (int m = 0; m < 4; ++m) {
        const float4* zp = (const float4*)(Z + (size_t)ids[m] * 8);
        sa = add4(sa, zp[0]);
        sb = add4(sb, zp[1]);
    }
#pragma unroll
    for (int off = 32; off > 0; off >>= 1) {
        sa = add4(sa, shfl_down4(sa, off));
        sb = add4(sb, shfl_down4(sb, off));
    }
    __shared__ float4 la[4], lb[4];
    if (lane == 0) { la[wid] = sa; lb[wid] = sb; }
    __syncthreads();
    if (tid == 0) {
        float4 ta = la[0], tb = lb[0];
        for (int w = 1; w < 4; ++w) { ta = add4(ta, la[w]); tb = add4(tb, lb[w]); }
        float* tp = T + (size_t)blk * 8;
        tp[0] = ta.x; tp[1] = ta.y; tp[2] = ta.z; tp[3] = ta.w;
        tp[4] = tb.x; tp[5] = tb.y; tp[6] = tb.z; tp[7] = tb.w;
    }
}

// Exclusive scan of segment totals across the 16 segments of each projection.
__global__ __launch_bounds__(64) void segscan_kernel(const float* __restrict__ T,
                                                     float* __restrict__ Cc) {
    const int j = blockIdx.x, b = threadIdx.x;
    if (b < 8) {
        float run = 0.0f;
        for (int s = 0; s < NSEG; ++s) {
            size_t o = ((size_t)(j * NSEG + s)) * 8 + b;
            Cc[o] = run;
            run += T[o];
        }
    }
}

// Per-(proj,segment) 8-channel in-block scan + CDF-difference integral.
__global__ __launch_bounds__(256) void w1seg_kernel(const int* __restrict__ sorter,
                                                    const float* __restrict__ Z,
                                                    const float* __restrict__ pcs,
                                                    const float* __restrict__ Cc,
                                                    float* __restrict__ out) {
    const int blk = blockIdx.x;
    const int j = blk >> 4, s = blk & 15;
    const int tid = threadIdx.x, lane = tid & 63, wid = tid >> 6;
    const int base_g = s * SEGLEN + tid * 4;
    const int* srt = sorter + (size_t)j * HW;
    const float* pp = pcs + (size_t)j * HW;

    int4 id4 = *(const int4*)(srt + base_g);
    int ids[4] = {id4.x, id4.y, id4.z, id4.w};
    float4 za[4], zb[4];
#pragma unroll
    for (int m = 0; m < 4; ++m) {
        const float4* zp = (const float4*)(Z + (size_t)ids[m] * 8);
        za[m] = zp[0];
        zb[m] = zp[1];
    }
#pragma unroll
    for (int m = 1; m < 4; ++m) {
        za[m] = add4(za[m], za[m - 1]);
        zb[m] = add4(zb[m], zb[m - 1]);
    }
    const float4 tota = za[3], totb = zb[3];
    float4 ia = tota, ib = totb;
#pragma unroll
    for (int off = 1; off < 64; off <<= 1) {
        float4 ua = shfl_up4(ia, off);
        float4 ub = shfl_up4(ib, off);
        if (lane >= off) { ia = add4(ia, ua); ib = add4(ib, ub); }
    }
    __shared__ float4 lwa[4], lwb[4];
    __shared__ float lred[4];
    if (lane == 63) { lwa[wid] = ia; lwb[wid] = ib; }
    __syncthreads();
    const float* cp = Cc + (size_t)blk * 8;
    float4 ca = make_float4(cp[0], cp[1], cp[2], cp[3]);
    float4 cb = make_float4(cp[4], cp[5], cp[6], cp[7]);
#pragma unroll
    for (int w = 0; w < 4; ++w)
        if (w < wid) { ca = add4(ca, lwa[w]); cb = add4(cb, lwb[w]); }
    const float4 offa = add4(ca, sub4(ia, tota));
    const float4 offb = add4(cb, sub4(ib, totb));

    float4 p4 = *(const float4*)(pp + base_g);
    float p5 = (base_g + 4 < HW) ? pp[base_g + 4] : p4.w;
    float dd[4] = {p4.y - p4.x, p4.z - p4.y, p4.w - p4.z, p5 - p4.w};

    float accl = 0.0f;
#pragma unroll
    for (int m = 0; m < 4; ++m) {
        float4 cxa = add4(offa, za[m]);
        float4 cxb = add4(offb, zb[m]);
        float s8 = fabsf(cxa.x) + fabsf(cxa.y) + fabsf(cxa.z) + fabsf(cxa.w)
                 + fabsf(cxb.x) + fabsf(cxb.y) + fabsf(cxb.z) + fabsf(cxb.w);
        if (base_g + m < HW - 1) accl += s8 * dd[m];
    }
#pragma unroll
    for (int off = 32; off > 0; off >>= 1) accl += __shfl_down(accl, off);
    if (lane == 0) lred[wid] = accl;
    __syncthreads();
    if (tid == 0)
        atomicAdd(out, (lred[0] + lred[1] + lred[2] + lred[3]) * (1.0f / NPROJ));
}

extern "C" void kernel_launch(void* const* d_in, const int* in_sizes, int n_in,
                              void* d_out, int out_size, void* d_ws, size_t ws_size,
                              hipStream_t stream) {
    const float* X = (const float*)d_in[0];
    const float* Y = (const float*)d_in[1];
    const float* proj = (const float*)d_in[2];
    float* out = (float*)d_out;

    char* ws = (char*)d_ws;
    size_t off = 0;
    float* pcs = (float*)(ws + off);    off += (size_t)NPROJ * HW * sizeof(float);
    int* sorter = (int*)(ws + off);     off += (size_t)NPROJ * HW * sizeof(int);
    float* Xs = (float*)(ws + off);     off += (size_t)NB * HW * sizeof(float);
    float* Z = (float*)(ws + off);      off += (size_t)NB * HW * sizeof(float);
    float* T = (float*)(ws + off);      off += (size_t)NPROJ * NSEG * 8 * sizeof(float);
    float* Cc = (float*)(ws + off);     off += (size_t)NPROJ * NSEG * 8 * sizeof(float);
    float* Pmax = (float*)(ws + off);   off += NB * NCH * sizeof(float);
    int* Pidx = (int*)(ws + off);       off += NB * NCH * sizeof(int);
    float* Psx = (float*)(ws + off);    off += NB * NCH * sizeof(float);
    float* Psy = (float*)(ws + off);    off += NB * NCH * sizeof(float);
    float* fixAdd = (float*)(ws + off); off += NB * sizeof(float);
    int* fixIdx = (int*)(ws + off);     off += NB * sizeof(int);
    float* invX = (float*)(ws + off);   off += NB * sizeof(float);
    float* invY = (float*)(ws + off);   off += NB * sizeof(float);

    partial_kernel<<<NB * NCH, 256, 0, stream>>>(X, Y, Xs, Pmax, Pidx, Psx, Psy);
    combine_kernel<<<1, 256, 0, stream>>>(Pmax, Pidx, Psx, Psy, fixAdd, fixIdx, invX, invY, out);
    zprep_kernel<<<HW / 64, 64, 0, stream>>>(Xs, Y, fixAdd, fixIdx, invX, invY, Z);
    ranksort_kernel<<<NPROJ, 256, 0, stream>>>(proj, pcs, sorter);
    segsum_kernel<<<NPROJ * NSEG, 256, 0, stream>>>(sorter, Z, T);
    segscan_kernel<<<NPROJ, 64, 0, stream>>>(T, Cc);
    w1seg_kernel<<<NPROJ * NSEG, 256, 0, stream>>>(sorter, Z, pcs, Cc, out);
}

// Round 5
// 52.263 us; speedup vs baseline: 9.3206x; 1.4297x over previous
//
#include <hip/hip_runtime.h>
#include <math.h>

#define HW 16384
#define NPROJ 100
#define NB 8
#define NCH 32
#define CHLEN 512
#define EPSV 1e-6f

__device__ inline float4 add4(float4 a, float4 b) {
    return make_float4(a.x + b.x, a.y + b.y, a.z + b.z, a.w + b.w);
}
__device__ inline float4 sub4(float4 a, float4 b) {
    return make_float4(a.x - b.x, a.y - b.y, a.z - b.z, a.w - b.w);
}
__device__ inline float4 shfl_up4(float4 v, int off) {
    return make_float4(__shfl_up(v.x, off), __shfl_up(v.y, off),
                       __shfl_up(v.z, off), __shfl_up(v.w, off));
}
__device__ inline float4 shfl_up4w(float4 v, int off, int w) {
    return make_float4(__shfl_up(v.x, off, w), __shfl_up(v.y, off, w),
                       __shfl_up(v.z, off, w), __shfl_up(v.w, off, w));
}

// Stage 1: per-(batch, chunk) partials: Xs = x0+x1+x2 (stored), sum(Xs), sum(y0),
// chunk max/argmax of x0 (first-occurrence). Block 0 zeroes the output.
__global__ __launch_bounds__(256) void partial_kernel(const float* __restrict__ X,
                                                      const float* __restrict__ Y,
                                                      float* __restrict__ Xs,
                                                      float* __restrict__ Pmax,
                                                      int* __restrict__ Pidx,
                                                      float* __restrict__ Psx,
                                                      float* __restrict__ Psy,
                                                      float* __restrict__ out) {
    const int blk = blockIdx.x;
    const int b = blk >> 5, c = blk & 31;
    const int tid = threadIdx.x, lane = tid & 63, wid = tid >> 6;
    if (blk == 0 && tid == 0) out[0] = 0.0f;  // consumed only by wproj (later kernel)
    const float* xb = X + (size_t)b * 3 * HW;
    const float* yb = Y + (size_t)b * 3 * HW;
    const int base = c * CHLEN;

    float mv = -INFINITY;
    int mi = 0;
    float sx = 0.0f, sy = 0.0f;
#pragma unroll
    for (int k = 0; k < 2; ++k) {
        int p = base + k * 256 + tid;
        float x0 = xb[p], x1 = xb[HW + p], x2 = xb[2 * HW + p], y0 = yb[p];
        float s = x0 + x1 + x2;
        Xs[(size_t)b * HW + p] = s;
        sx += s;
        sy += y0;
        if (x0 > mv) { mv = x0; mi = p; }   // strict > keeps earliest p
    }
#pragma unroll
    for (int off = 32; off > 0; off >>= 1) {
        float ov = __shfl_down(mv, off);
        int oi = __shfl_down(mi, off);
        sx += __shfl_down(sx, off);
        sy += __shfl_down(sy, off);
        if (ov > mv || (ov == mv && oi < mi)) { mv = ov; mi = oi; }
    }
    __shared__ float lmv[4], lsx[4], lsy[4];
    __shared__ int lmi[4];
    if (lane == 0) { lmv[wid] = mv; lmi[wid] = mi; lsx[wid] = sx; lsy[wid] = sy; }
    __syncthreads();
    if (tid == 0) {
        for (int w = 1; w < 4; ++w) {
            if (lmv[w] > lmv[0] || (lmv[w] == lmv[0] && lmi[w] < lmi[0])) {
                lmv[0] = lmv[w];
                lmi[0] = lmi[w];
            }
            lsx[0] += lsx[w];
            lsy[0] += lsy[w];
        }
        Pmax[blk] = lmv[0];
        Pidx[blk] = lmi[0];
        Psx[blk] = lsx[0];
        Psy[blk] = lsy[0];
    }
}

// Stage 2 (combine folded in): every block redundantly reduces the 8x32 partials,
// then builds Z[p][b] = (Xs+fix)*invX - Y0*invY, pixel-major float8 (32B/pixel).
__global__ __launch_bounds__(256) void zprep_kernel(const float* __restrict__ Pmax,
                                                    const int* __restrict__ Pidx,
                                                    const float* __restrict__ Psx,
                                                    const float* __restrict__ Psy,
                                                    const float* __restrict__ Xs,
                                                    const float* __restrict__ Y,
                                                    float* __restrict__ Z) {
    __shared__ float sInvX[8], sInvY[8], sFa[8];
    __shared__ int sFi[8];
    const int tid = threadIdx.x;
    const int c = tid & 31;
    {
        const int b = tid >> 5;
        float mv = Pmax[tid];
        int mi = Pidx[tid];
        float sx = Psx[tid];
        float sy = Psy[tid];
#pragma unroll
        for (int off = 16; off > 0; off >>= 1) {
            float ov = __shfl_down(mv, off, 32);
            int oi = __shfl_down(mi, off, 32);
            float osx = __shfl_down(sx, off, 32);
            float osy = __shfl_down(sy, off, 32);
            if (ov > mv || (ov == mv && oi < mi)) { mv = ov; mi = oi; }
            sx += osx;
            sy += osy;
        }
        if (c == 0) {
            float fa = (mv < EPSV) ? (EPSV - mv) : 0.0f;
            sFa[b] = fa;
            sFi[b] = mi;
            sInvX[b] = 1.0f / (sx + fa);
            sInvY[b] = 1.0f / sy;
        }
    }
    __syncthreads();
    const int p = blockIdx.x * 256 + tid;
    float z[8];
#pragma unroll
    for (int b = 0; b < 8; ++b) {
        float s = Xs[(size_t)b * HW + p];
        if (p == sFi[b]) s += sFa[b];
        z[b] = s * sInvX[b] - Y[(size_t)b * 3 * HW + p] * sInvY[b];
    }
    float4* zp = (float4*)(Z + (size_t)p * 8);
    zp[0] = make_float4(z[0], z[1], z[2], z[3]);
    zp[1] = make_float4(z[4], z[5], z[6], z[7]);
}

// One block per projection: analytic ranksort into LDS (spc/sid), then 8-channel
// block-wide scan + CDF-difference integral straight out of LDS. sorter/pcs
// never touch global memory; Z gathered exactly once.
__global__ __launch_bounds__(1024) void wproj_kernel(const float* __restrict__ proj,
                                                     const float* __restrict__ Z,
                                                     float* __restrict__ out) {
    __shared__ float spc[HW];            // 64 KiB sorted pc values
    __shared__ unsigned short sid[HW];   // 32 KiB sorted pixel ids
    __shared__ int c_t[255];
    __shared__ unsigned char e_t[255];
    __shared__ float4 lwa[17], lwb[17];  // wave totals -> exclusive prefixes (+ total)
    __shared__ float lred[16];

    const int jp = blockIdx.x;
    const int tid = threadIdx.x, lane = tid & 63, wid = tid >> 6;
    float a = proj[jp];
    float b = proj[NPROJ + jp];
    float inv = 1.0f / sqrtf(a * a + b * b);
    const float an = a * inv, bn = b * inv;
    const float ap = fabsf(an), bp = fabsf(bn);
    const bool flipi = (an < 0.0f), flipj = (bn < 0.0f);

    if (bp == 0.0f) {
        // degenerate: order depends only on ii; pos = i2*128 + j2
        for (int t = tid; t < HW; t += 1024) {
            int i2 = t >> 7, j2 = t & 127;
            int ii = flipi ? 127 - i2 : i2;
            int jj = flipj ? 127 - j2 : j2;
            spc[t] = (float)ii * an + (float)jj * bn;
            sid[t] = (unsigned short)(ii * 128 + jj);
        }
    } else {
        if (tid < 255) {
            int d = tid - 127;
            double v = (double)d * ((double)ap / (double)bp);
            double cv = ceil(v);
            e_t[tid] = (cv == v) ? 1 : 0;
            c_t[tid] = (int)fmin(fmax(cv, -128.0), 129.0);
        }
        __syncthreads();
        if (tid < 128) {
            const int j2 = tid;
            const int jj = flipj ? 127 - j2 : j2;
            const float vj = (float)jj * bn;
            int wsum = 0;
#pragma unroll 8
            for (int dd = 0; dd <= 127; ++dd)
                wsum += min(max(c_t[dd] + j2, 0), 128);
            int tsum = 0;
            for (int i2 = 0; i2 < 128; ++i2) {
                if (i2 > 0) {
                    int dd_new = i2 + 127;
                    int dd_old = i2 - 1;
                    int cn = c_t[dd_new];
                    wsum += min(max(cn + j2, 0), 128);
                    wsum -= min(max(c_t[dd_old] + j2, 0), 128);
                    if (e_t[dd_new]) {
                        int tj = j2 + cn;
                        if (tj >= 0 && tj < 128) tsum++;
                    }
                }
                int pos = wsum + tsum;
                int ii = flipi ? 127 - i2 : i2;
                spc[pos] = (float)ii * an + vj;
                sid[pos] = (unsigned short)(ii * 128 + jj);
            }
        }
    }
    __syncthreads();

    // phase 2: 4 chunks x (1024 threads x 4 pixels); 8-channel scan + integral
    float4 runa = make_float4(0, 0, 0, 0), runb = runa;
    float acc = 0.0f;
#pragma unroll 1
    for (int ch = 0; ch < 4; ++ch) {
        const int base = ch * 4096 + tid * 4;
        float4 za[4], zb[4];
#pragma unroll
        for (int m = 0; m < 4; ++m) {
            int id = (int)sid[base + m];
            const float4* zp = (const float4*)(Z + (size_t)id * 8);
            za[m] = zp[0];
            zb[m] = zp[1];
        }
#pragma unroll
        for (int m = 1; m < 4; ++m) {
            za[m] = add4(za[m], za[m - 1]);
            zb[m] = add4(zb[m], zb[m - 1]);
        }
        float4 ia = za[3], ib = zb[3];
#pragma unroll
        for (int off = 1; off < 64; off <<= 1) {
            float4 ua = shfl_up4(ia, off);
            float4 ub = shfl_up4(ib, off);
            if (lane >= off) { ia = add4(ia, ua); ib = add4(ib, ub); }
        }
        if (lane == 63) { lwa[wid] = ia; lwb[wid] = ib; }
        __syncthreads();
        if (tid < 16) {  // second-level 16-lane scan of wave totals
            float4 va = lwa[tid], vb = lwb[tid];
            float4 sa = va, sb = vb;
#pragma unroll
            for (int off = 1; off < 16; off <<= 1) {
                float4 ua = shfl_up4w(sa, off, 16);
                float4 ub = shfl_up4w(sb, off, 16);
                if (tid >= off) { sa = add4(sa, ua); sb = add4(sb, ub); }
            }
            lwa[tid] = sub4(sa, va);  // exclusive
            lwb[tid] = sub4(sb, vb);
            if (tid == 15) { lwa[16] = sa; lwb[16] = sb; }  // block total
        }
        __syncthreads();
        float4 offa = add4(add4(runa, lwa[wid]), sub4(ia, za[3]));
        float4 offb = add4(add4(runb, lwb[wid]), sub4(ib, zb[3]));
        runa = add4(runa, lwa[16]);
        runb = add4(runb, lwb[16]);
#pragma unroll
        for (int m = 0; m < 4; ++m) {
            int k = base + m;
            if (k < HW - 1) {
                float d = spc[k + 1] - spc[k];
                float4 cxa = add4(offa, za[m]);
                float4 cxb = add4(offb, zb[m]);
                float s8 = fabsf(cxa.x) + fabsf(cxa.y) + fabsf(cxa.z) + fabsf(cxa.w)
                         + fabsf(cxb.x) + fabsf(cxb.y) + fabsf(cxb.z) + fabsf(cxb.w);
                acc += s8 * d;
            }
        }
        __syncthreads();  // protect lwa/lwb reuse next chunk
    }

#pragma unroll
    for (int off = 32; off > 0; off >>= 1) acc += __shfl_down(acc, off);
    if (lane == 0) lred[wid] = acc;
    __syncthreads();
    if (tid == 0) {
        float r = 0.0f;
        for (int w = 0; w < 16; ++w) r += lred[w];
        atomicAdd(out, r * (1.0f / NPROJ));
    }
}

extern "C" void kernel_launch(void* const* d_in, const int* in_sizes, int n_in,
                              void* d_out, int out_size, void* d_ws, size_t ws_size,
                              hipStream_t stream) {
    const float* X = (const float*)d_in[0];
    const float* Y = (const float*)d_in[1];
    const float* proj = (const float*)d_in[2];
    float* out = (float*)d_out;

    char* ws = (char*)d_ws;
    size_t off = 0;
    float* Xs = (float*)(ws + off);     off += (size_t)NB * HW * sizeof(float);
    float* Z = (float*)(ws + off);      off += (size_t)NB * HW * sizeof(float);
    float* Pmax = (float*)(ws + off);   off += NB * NCH * sizeof(float);
    int* Pidx = (int*)(ws + off);       off += NB * NCH * sizeof(int);
    float* Psx = (float*)(ws + off);    off += NB * NCH * sizeof(float);
    float* Psy = (float*)(ws + off);    off += NB * NCH * sizeof(float);

    partial_kernel<<<NB * NCH, 256, 0, stream>>>(X, Y, Xs, Pmax, Pidx, Psx, Psy, out);
    zprep_kernel<<<HW / 256, 256, 0, stream>>>(Pmax, Pidx, Psx, Psy, Xs, Y, Z);
    wproj_kernel<<<NPROJ, 1024, 0, stream>>>(proj, Z, out);
}